// Round 3
// baseline (385.165 us; speedup 1.0000x reference)
//
#include <hip/hip_runtime.h>
#include <math.h>

// Problem constants
#define BB 2
#define LL 512
#define HH 768
#define EE 512
#define RR 32768
#define H2 384
#define MM 1024   // B*E entity rows
#define GRID 512  // 2 blocks/CU; co-residency guaranteed (LDS 36.9KB -> >=3/CU)

typedef __attribute__((ext_vector_type(8))) short     bf16x8;  // MFMA A/B frag
typedef __attribute__((ext_vector_type(4))) float     f32x4;   // MFMA C/D frag
typedef __attribute__((ext_vector_type(8))) unsigned short u16x8;

__device__ __forceinline__ unsigned short f2bf(float f) {
    unsigned int u = __float_as_uint(f);
    u = (u + 0x7FFFu + ((u >> 16) & 1u)) >> 16;   // round-to-nearest-even
    return (unsigned short)u;
}

// Device-scope grid barrier: one counter per barrier slot (no reset needed).
__device__ __forceinline__ void gbar(unsigned* bars, int idx) {
    __syncthreads();
    if (threadIdx.x == 0) {
        __threadfence();                                  // release my writes
        if (atomicAdd(&bars[idx], 1u) + 1u < (unsigned)GRID) {
            while (atomicAdd(&bars[idx], 0u) < (unsigned)GRID)
                __builtin_amdgcn_s_sleep(4);
        }
        __threadfence();                                  // acquire others'
    }
    __syncthreads();
}

__global__ __launch_bounds__(64) void init_bars(unsigned* bars) {
    if (threadIdx.x < 8) bars[threadIdx.x] = 0u;
}

// ---------------------------------------------------------------------------
// prep task (stage 0):
//   [0,2016)    transpose+convert weights [K][N] fp32 -> [N][K] bf16
//   [2016,3040) gather hidden[b, ent_start] -> Hbf bf16 [1024][768]
//   [3040,3064) embc[l][n] = b1[n] + sum_k emb[l][k]*W1[768+k][n]
//   3064        zero hlin/tlin accumulators + out[0]
// ---------------------------------------------------------------------------
__device__ void prep_task(int task,
    const float* hW1, const float* tW1, const float* hW2, const float* tW2,
    const float* bilW,
    unsigned short* W1ht, unsigned short* W1tt,
    unsigned short* W2ht, unsigned short* W2tt,
    unsigned short* bW0t, unsigned short* bW1t,
    const float* hidden, const int* ent_start, const int* ent_label,
    const float* emb, const float* hb1, const float* tb1,
    unsigned short* Hbf, float* embc,
    float* hlin, float* tlin, float* out,
    unsigned short* SBu, float* SBf)
{
    const int t = threadIdx.x;

    if (task == 3064) {
        const float4 z = {0.f, 0.f, 0.f, 0.f};
        ((float4*)hlin)[t] = z; ((float4*)hlin)[256 + t] = z;
        ((float4*)tlin)[t] = z; ((float4*)tlin)[256 + t] = z;
        if (t == 0) out[0] = 0.f;
        return;
    }

    if (task >= 3040) {
        // embc fold; red aliased into SBf[kg*192 + ...]
        const int eb = task - 3040;          // 0..23
        const int tc = t & 63;
        const int kg = t >> 6;               // 0..3
        const int n = eb * 64 + tc;          // 0..1535
        const float* W = (n < 768) ? hW1 : tW1;
        const int cc = (n < 768) ? n : n - 768;
        float a0 = 0.f, a1 = 0.f, a2 = 0.f;
        const int kbeg = kg * 192;
        #pragma unroll 8
        for (int k = kbeg; k < kbeg + 192; ++k) {
            const float w = W[(size_t)(768 + k) * 768 + cc];
            a0 += emb[k] * w;
            a1 += emb[768 + k] * w;
            a2 += emb[1536 + k] * w;
        }
        SBf[kg * 192 + 0 * 64 + tc] = a0;
        SBf[kg * 192 + 1 * 64 + tc] = a1;
        SBf[kg * 192 + 2 * 64 + tc] = a2;
        __syncthreads();
        if (kg == 0) {
            const float b = (n < 768) ? hb1[n] : tb1[n - 768];
            #pragma unroll
            for (int l = 0; l < 3; ++l) {
                embc[l * 1536 + n] = b + SBf[0 * 192 + l * 64 + tc]
                    + SBf[1 * 192 + l * 64 + tc] + SBf[2 * 192 + l * 64 + tc]
                    + SBf[3 * 192 + l * 64 + tc];
            }
        }
        return;
    }

    if (task >= 2016) {
        const int m = task - 2016;           // 0..1023
        if (t >= 96) return;
        const int b = m >> 9;
        const int idx = ent_start[m];
        const float4* s = (const float4*)(hidden + (size_t)(b * LL + idx) * HH);
        const float4 v0 = s[2 * t];
        const float4 v1 = s[2 * t + 1];
        u16x8 o;
        o[0] = f2bf(v0.x); o[1] = f2bf(v0.y); o[2] = f2bf(v0.z); o[3] = f2bf(v0.w);
        o[4] = f2bf(v1.x); o[5] = f2bf(v1.y); o[6] = f2bf(v1.z); o[7] = f2bf(v1.w);
        *(u16x8*)(Hbf + (size_t)m * 768 + 8 * t) = o;
        return;
    }

    // weight transpose (32x32 tile); T aliased into SBu (32*40 ushorts)
    const float* src; unsigned short* dst; int K, N, tile;
    if (task < 576)       { src = hW1;            dst = W1ht; K = 768; N = 768; tile = task; }
    else if (task < 1152) { src = tW1;            dst = W1tt; K = 768; N = 768; tile = task - 576; }
    else if (task < 1440) { src = hW2;            dst = W2ht; K = 768; N = 384; tile = task - 1152; }
    else if (task < 1728) { src = tW2;            dst = W2tt; K = 768; N = 384; tile = task - 1440; }
    else if (task < 1872) { src = bilW;           dst = bW0t; K = 384; N = 384; tile = task - 1728; }
    else                  { src = bilW + 384*384; dst = bW1t; K = 384; N = 384; tile = task - 1872; }
    const int tn = N >> 5;
    const int n0 = (tile % tn) * 32;
    const int k0 = (tile / tn) * 32;

    const int r  = t >> 3;           // 0..31 (k within tile)
    const int c4 = (t & 7) * 4;      // 0..28 (n within tile)
    const float4 g = *(const float4*)(src + (size_t)(k0 + r) * N + n0 + c4);
    SBu[(c4 + 0) * 40 + r] = f2bf(g.x);
    SBu[(c4 + 1) * 40 + r] = f2bf(g.y);
    SBu[(c4 + 2) * 40 + r] = f2bf(g.z);
    SBu[(c4 + 3) * 40 + r] = f2bf(g.w);
    __syncthreads();
    const int n  = t >> 3;           // 0..31
    const int k4 = (t & 7) * 4;      // 0..28
    *(ushort4*)(dst + (size_t)(n0 + n) * K + k0 + k4) = *(ushort4*)&SBu[n * 40 + k4];
}

// ---------------------------------------------------------------------------
// One 64x64 GEMM tile (4 waves 2x2, 16x16x32 MFMA, K_STEP=64, LDS dbuf,
// one raw s_barrier per K-step — prefetch loads stay in flight across it).
// ---------------------------------------------------------------------------
template<bool RELU, bool BIAS, bool EB, bool WF32, bool WBF16, bool O2, bool LIN>
__device__ __forceinline__ void gemm_stage(
    int ntiles, int nx,
    const unsigned short* __restrict__ A, int lda, int aoff1,
    const unsigned short* __restrict__ Bt0, const unsigned short* __restrict__ Bt1,
    int ldb, int bt_mrow, int Nh,
    const float* __restrict__ bias0, const float* __restrict__ bias1,
    const float* __restrict__ embc, const int* __restrict__ labels,
    const float* __restrict__ linW, float* __restrict__ hlin, float* __restrict__ tlin,
    int K, float* __restrict__ Cf, unsigned short* __restrict__ Cb, int ldc,
    unsigned short* As, unsigned short* Bs)
{
    const int tile = blockIdx.x;
    if (tile >= ntiles) return;
    const int tid = threadIdx.x;
    const int n0 = (tile % nx) * 64;
    const int m0 = (tile / nx) * 64;
    const int hf = (n0 >= Nh) ? 1 : 0;
    const unsigned short* Bt = hf ? Bt1 : Bt0;
    const int nc0 = n0 - (hf ? Nh : 0);
    const int aoff = hf ? aoff1 : 0;

    const int sr = tid >> 2;            // 0..63
    const int sk = (tid & 3) * 16;      // 0,16,32,48

    const unsigned short* Ap = A + (size_t)(m0 + sr) * lda + aoff + sk;
    const unsigned short* Bp = Bt + (size_t)((m0 >> 9) * bt_mrow + nc0 + sr) * ldb + sk;

    const int lane = tid & 63;
    const int wave = tid >> 6;
    const int wm = (wave & 1) * 32;
    const int wn = (wave >> 1) * 32;
    const int l15 = lane & 15;
    const int quad = lane >> 4;

    f32x4 acc00 = {}, acc01 = {}, acc10 = {}, acc11 = {};

    // prologue: tile 0 -> regs -> LDS buf0
    u16x8 a0v = *(const u16x8*)(Ap);
    u16x8 a1v = *(const u16x8*)(Ap + 8);
    u16x8 b0v = *(const u16x8*)(Bp);
    u16x8 b1v = *(const u16x8*)(Bp + 8);
    const int swo = sr * 72 + sk;
    *(u16x8*)&As[swo] = a0v; *(u16x8*)&As[swo + 8] = a1v;
    *(u16x8*)&Bs[swo] = b0v; *(u16x8*)&Bs[swo + 8] = b1v;

    const int NT = K >> 6;
    const int aro = quad * 8;
    int cur = 0;
    for (int it = 0; it < NT; ++it) {
        if (it + 1 < NT) {              // issue next tile's loads (in flight)
            const int ko = (it + 1) * 64;
            a0v = *(const u16x8*)(Ap + ko); a1v = *(const u16x8*)(Ap + ko + 8);
            b0v = *(const u16x8*)(Bp + ko); b1v = *(const u16x8*)(Bp + ko + 8);
        }
        asm volatile("s_waitcnt lgkmcnt(0)" ::: "memory");
        __builtin_amdgcn_s_barrier();
        __builtin_amdgcn_sched_barrier(0);
        const unsigned short* Ac = As + cur * 4608;
        const unsigned short* Bc = Bs + cur * 4608;
        const bf16x8 fa0 = *(const bf16x8*)&Ac[(wm + l15) * 72 + aro];
        const bf16x8 fa1 = *(const bf16x8*)&Ac[(wm + 16 + l15) * 72 + aro];
        const bf16x8 fb0 = *(const bf16x8*)&Bc[(wn + l15) * 72 + aro];
        const bf16x8 fb1 = *(const bf16x8*)&Bc[(wn + 16 + l15) * 72 + aro];
        const bf16x8 ga0 = *(const bf16x8*)&Ac[(wm + l15) * 72 + aro + 32];
        const bf16x8 ga1 = *(const bf16x8*)&Ac[(wm + 16 + l15) * 72 + aro + 32];
        const bf16x8 gb0 = *(const bf16x8*)&Bc[(wn + l15) * 72 + aro + 32];
        const bf16x8 gb1 = *(const bf16x8*)&Bc[(wn + 16 + l15) * 72 + aro + 32];
        acc00 = __builtin_amdgcn_mfma_f32_16x16x32_bf16(fa0, fb0, acc00, 0, 0, 0);
        acc01 = __builtin_amdgcn_mfma_f32_16x16x32_bf16(fa0, fb1, acc01, 0, 0, 0);
        acc10 = __builtin_amdgcn_mfma_f32_16x16x32_bf16(fa1, fb0, acc10, 0, 0, 0);
        acc11 = __builtin_amdgcn_mfma_f32_16x16x32_bf16(fa1, fb1, acc11, 0, 0, 0);
        acc00 = __builtin_amdgcn_mfma_f32_16x16x32_bf16(ga0, gb0, acc00, 0, 0, 0);
        acc01 = __builtin_amdgcn_mfma_f32_16x16x32_bf16(ga0, gb1, acc01, 0, 0, 0);
        acc10 = __builtin_amdgcn_mfma_f32_16x16x32_bf16(ga1, gb0, acc10, 0, 0, 0);
        acc11 = __builtin_amdgcn_mfma_f32_16x16x32_bf16(ga1, gb1, acc11, 0, 0, 0);
        if (it + 1 < NT) {
            unsigned short* Aw = As + (cur ^ 1) * 4608;
            unsigned short* Bw = Bs + (cur ^ 1) * 4608;
            *(u16x8*)&Aw[swo] = a0v; *(u16x8*)&Aw[swo + 8] = a1v;
            *(u16x8*)&Bw[swo] = b0v; *(u16x8*)&Bw[swo + 8] = b1v;
        }
        cur ^= 1;
    }

    // epilogue: C/D layout col=lane&15, row=quad*4+reg
    float bias_v0 = 0.f, bias_v1 = 0.f;
    if (BIAS) {
        const float* bb = hf ? bias1 : bias0;
        bias_v0 = bb[nc0 + wn + l15];
        bias_v1 = bb[nc0 + wn + 16 + l15];
    }
    const int col0 = n0 + wn + l15;
    const int col1 = col0 + 16;
    int colw0 = col0, colw1 = col1;
    if (O2) {
        colw0 = 2 * (nc0 + wn + l15) + hf;
        colw1 = 2 * (nc0 + wn + 16 + l15) + hf;
    }
    float2 lw0 = {0.f, 0.f}, lw1 = {0.f, 0.f};
    float* lout = nullptr;
    if (LIN) {
        lw0 = ((const float2*)linW)[col0];
        lw1 = ((const float2*)linW)[col1];
        lout = hf ? tlin : hlin;
    }
    const f32x4 accs[2][2] = {{acc00, acc01}, {acc10, acc11}};
    #pragma unroll
    for (int mi = 0; mi < 2; ++mi) {
        #pragma unroll
        for (int r = 0; r < 4; ++r) {
            const int row = m0 + wm + mi * 16 + quad * 4 + r;
            float v0 = accs[mi][0][r];
            float v1 = accs[mi][1][r];
            if (BIAS) { v0 += bias_v0; v1 += bias_v1; }
            if (EB) {
                const int lab = labels[row];
                v0 += embc[lab * 1536 + col0];
                v1 += embc[lab * 1536 + col1];
            }
            if (RELU) { v0 = fmaxf(v0, 0.f); v1 = fmaxf(v1, 0.f); }
            if (WF32) {
                Cf[(size_t)row * ldc + colw0] = v0;
                Cf[(size_t)row * ldc + colw1] = v1;
            }
            if (WBF16) {
                Cb[(size_t)row * ldc + colw0] = f2bf(v0);
                Cb[(size_t)row * ldc + colw1] = f2bf(v1);
            }
            if (LIN) {
                float s0 = v0 * lw0.x + v1 * lw1.x;
                float s1 = v0 * lw0.y + v1 * lw1.y;
                #pragma unroll
                for (int o = 8; o >= 1; o >>= 1) {
                    s0 += __shfl_xor(s0, o, 64);
                    s1 += __shfl_xor(s1, o, 64);
                }
                if (l15 == 0) {
                    atomicAdd(&lout[2 * row],     s0);
                    atomicAdd(&lout[2 * row + 1], s1);
                }
            }
        }
    }
}

// ---------------------------------------------------------------------------
// The fused persistent kernel: 6 stages, 5 grid barriers.
// ---------------------------------------------------------------------------
__global__ __launch_bounds__(256) void fused(
    const float* __restrict__ hidden, const int* __restrict__ ent_start,
    const int* __restrict__ ent_label, const int* __restrict__ rel_head,
    const int* __restrict__ rel_tail, const int* __restrict__ rel_label,
    const float* __restrict__ emb,
    const float* __restrict__ hW1, const float* __restrict__ hb1,
    const float* __restrict__ hW2, const float* __restrict__ hb2,
    const float* __restrict__ tW1, const float* __restrict__ tb1,
    const float* __restrict__ tW2, const float* __restrict__ tb2,
    const float* __restrict__ bilW, const float* __restrict__ linW,
    const float* __restrict__ lin_b,
    unsigned short* __restrict__ Hbf, unsigned short* __restrict__ Y1bf,
    unsigned short* __restrict__ HTbf, unsigned short* __restrict__ hWbf,
    float* __restrict__ Stab,
    unsigned short* __restrict__ W1ht, unsigned short* __restrict__ W1tt,
    unsigned short* __restrict__ W2ht, unsigned short* __restrict__ W2tt,
    unsigned short* __restrict__ bW0t, unsigned short* __restrict__ bW1t,
    float* __restrict__ embc, float* __restrict__ hlin, float* __restrict__ tlin,
    unsigned* __restrict__ bars, float* __restrict__ out)
{
    __shared__ __align__(16) unsigned short SB[2][2][4608];   // 36,864 B
    unsigned short* As = &SB[0][0][0];
    unsigned short* Bs = &SB[1][0][0];
    const int tid = threadIdx.x;

    // ---- stage 0: prep (3065 tasks, strided)
    for (int task = blockIdx.x; task < 3065; task += GRID) {
        prep_task(task, hW1, tW1, hW2, tW2, bilW,
                  W1ht, W1tt, W2ht, W2tt, bW0t, bW1t,
                  hidden, ent_start, ent_label, emb, hb1, tb1,
                  Hbf, embc, hlin, tlin, out,
                  As, (float*)As);
        __syncthreads();
    }
    gbar(bars, 0);

    // ---- stage 1: layer1  Y1 = relu(Hbf @ [W1h'|W1t'] + embc[lab])
    gemm_stage<true, false, true, false, true, false, false>(
        384, 24, Hbf, 768, 0, W1ht, W1tt, 768, 0, 768,
        nullptr, nullptr, embc, ent_label, nullptr, nullptr, nullptr,
        768, nullptr, Y1bf, 1536, As, Bs);
    gbar(bars, 1);

    // ---- stage 2: layer2  HTbf = relu(Y1 @ [W2h|W2t] + b2)  (+fused lin_proj)
    gemm_stage<true, true, false, false, true, false, true>(
        192, 12, Y1bf, 1536, 768, W2ht, W2tt, 768, 0, 384,
        hb2, tb2, nullptr, nullptr, linW, hlin, tlin,
        768, nullptr, HTbf, 768, As, Bs);
    gbar(bars, 2);

    // ---- stage 3: bilinear left  hWbf = heads @ bil_W[o]
    gemm_stage<false, false, false, false, true, false, false>(
        192, 12, HTbf, 768, 0, bW0t, bW1t, 384, 0, 384,
        nullptr, nullptr, nullptr, nullptr, nullptr, nullptr, nullptr,
        384, nullptr, hWbf, 768, As, Bs);
    gbar(bars, 3);

    // ---- stage 4: score table (o-interleaved)  Stab[mh][2t+o]
    gemm_stage<false, false, false, true, false, true, false>(
        256, 16, hWbf, 768, 384, HTbf + 384, HTbf + 384, 768, 512, 512,
        nullptr, nullptr, nullptr, nullptr, nullptr, nullptr, nullptr,
        384, Stab, nullptr, 1024, As, Bs);
    gbar(bars, 4);

    // ---- stage 5: rel gather + CE reduce (128 rels per block)
    {
        float ce = 0.f;
        if (tid < 128) {
            const int i = blockIdx.x * 128 + tid;     // 0..65535
            const int b = i >> 15;
            const int h = rel_head[i];
            const int t = rel_tail[i];
            const int lab = rel_label[i];
            const int mh = (b << 9) + h;
            const int mt = (b << 9) + t;
            const float2 hl = ((const float2*)hlin)[mh];
            const float2 tl = ((const float2*)tlin)[mt];
            const float2 zz = *(const float2*)(Stab + (size_t)mh * 1024 + 2 * t);
            const float z0 = zz.x + hl.x + tl.x + lin_b[0];
            const float z1 = zz.y + hl.y + tl.y + lin_b[1];
            out[1 + 2 * (size_t)i] = z0;
            out[2 + 2 * (size_t)i] = z1;
            const float mx = fmaxf(z0, z1);
            const float mn = fminf(z0, z1);
            const float lse = mx + log1pf(expf(mn - mx));
            ce = lse - (lab ? z1 : z0);
        }
        #pragma unroll
        for (int o = 32; o >= 1; o >>= 1) ce += __shfl_xor(ce, o, 64);
        float* wsum = (float*)As;
        if ((tid & 63) == 0) wsum[tid >> 6] = ce;
        __syncthreads();
        if (tid == 0) {
            const float bs = wsum[0] + wsum[1] + wsum[2] + wsum[3];
            atomicAdd(out, bs * (1.0f / (float)RR));
        }
    }
}

// ---------------------------------------------------------------------------
extern "C" void kernel_launch(void* const* d_in, const int* in_sizes, int n_in,
                              void* d_out, int out_size, void* d_ws, size_t ws_size,
                              hipStream_t stream) {
    const float* hidden    = (const float*)d_in[0];
    const int*   ent_start = (const int*)d_in[1];
    const int*   ent_label = (const int*)d_in[2];
    const int*   rel_head  = (const int*)d_in[3];
    const int*   rel_tail  = (const int*)d_in[4];
    const int*   rel_label = (const int*)d_in[5];
    const float* emb       = (const float*)d_in[6];
    const float* head_W1   = (const float*)d_in[7];
    const float* head_b1   = (const float*)d_in[8];
    const float* head_W2   = (const float*)d_in[9];
    const float* head_b2   = (const float*)d_in[10];
    const float* tail_W1   = (const float*)d_in[11];
    const float* tail_b1   = (const float*)d_in[12];
    const float* tail_W2   = (const float*)d_in[13];
    const float* tail_b2   = (const float*)d_in[14];
    const float* bil_W     = (const float*)d_in[15];
    const float* lin_W     = (const float*)d_in[16];
    const float* lin_b     = (const float*)d_in[17];
    float* out = (float*)d_out;

    // Workspace carve-up (256B-aligned chunks)
    char* w = (char*)d_ws;
    auto carve = [&](size_t bytes) {
        char* p = w; w += (bytes + 255) & ~(size_t)255; return p;
    };
    unsigned short* Hbf  = (unsigned short*)carve((size_t)MM * 768 * 2);
    unsigned short* Y1bf = (unsigned short*)carve((size_t)MM * 1536 * 2);
    unsigned short* HTbf = (unsigned short*)carve((size_t)MM * 768 * 2);
    unsigned short* hWbf = (unsigned short*)carve((size_t)MM * 768 * 2);
    float*          Stab = (float*)carve((size_t)MM * 1024 * 4);
    unsigned short* W1ht = (unsigned short*)carve((size_t)768 * 768 * 2);
    unsigned short* W1tt = (unsigned short*)carve((size_t)768 * 768 * 2);
    unsigned short* W2ht = (unsigned short*)carve((size_t)384 * 768 * 2);
    unsigned short* W2tt = (unsigned short*)carve((size_t)384 * 768 * 2);
    unsigned short* bW0t = (unsigned short*)carve((size_t)384 * 384 * 2);
    unsigned short* bW1t = (unsigned short*)carve((size_t)384 * 384 * 2);
    float*          embc = (float*)carve((size_t)3 * 1536 * 4);
    float*          hlin = (float*)carve(2048 * 4);
    float*          tlin = (float*)carve(2048 * 4);
    unsigned*       bars = (unsigned*)carve(8 * 4);

    init_bars<<<1, 64, 0, stream>>>(bars);

    fused<<<GRID, 256, 0, stream>>>(
        hidden, ent_start, ent_label, rel_head, rel_tail, rel_label, emb,
        head_W1, head_b1, head_W2, head_b2,
        tail_W1, tail_b1, tail_W2, tail_b2,
        bil_W, lin_W, lin_b,
        Hbf, Y1bf, HTbf, hWbf, Stab,
        W1ht, W1tt, W2ht, W2tt, bW0t, bW1t,
        embc, hlin, tlin, bars, out);
}

// Round 4
// 169.543 us; speedup vs baseline: 2.2718x; 2.2718x over previous
//
#include <hip/hip_runtime.h>
#include <math.h>

// Problem constants
#define BB 2
#define LL 512
#define HH 768
#define EE 512
#define RR 32768
#define H2 384
#define MM 1024   // B*E entity rows

typedef __attribute__((ext_vector_type(8))) short     bf16x8;  // MFMA A/B frag
typedef __attribute__((ext_vector_type(4))) float     f32x4;   // MFMA C/D frag
typedef __attribute__((ext_vector_type(8))) unsigned short u16x8;

__device__ __forceinline__ unsigned short f2bf(float f) {
    unsigned int u = __float_as_uint(f);
    u = (u + 0x7FFFu + ((u >> 16) & 1u)) >> 16;   // round-to-nearest-even
    return (unsigned short)u;
}
__device__ __forceinline__ float bf2f(unsigned short u) {
    return __uint_as_float((unsigned)u << 16);
}

// ---------------------------------------------------------------------------
// prep:
//   blocks [0,2016)    transpose+convert weights [K][N] fp32 -> [N][K] bf16
//   blocks [2016,3040) gather hidden[b, ent_start] -> Hbf bf16 [1024][768]
//   blocks [3040,3064) embc[l][n] = b1[n] + sum_k emb[l][k]*W1[768+k][n]
//   block  3064        zero hlin/tlin accumulators + out[0]
// ---------------------------------------------------------------------------
__global__ __launch_bounds__(256) void prep(
    const float* __restrict__ hW1, const float* __restrict__ tW1,
    const float* __restrict__ hW2, const float* __restrict__ tW2,
    const float* __restrict__ bilW,
    unsigned short* __restrict__ W1ht, unsigned short* __restrict__ W1tt,
    unsigned short* __restrict__ W2ht, unsigned short* __restrict__ W2tt,
    unsigned short* __restrict__ bW0t, unsigned short* __restrict__ bW1t,
    const float* __restrict__ hidden, const int* __restrict__ ent_start,
    const int* __restrict__ ent_label, const float* __restrict__ emb,
    const float* __restrict__ hb1, const float* __restrict__ tb1,
    unsigned short* __restrict__ Hbf, float* __restrict__ embc,
    float* __restrict__ hlin, float* __restrict__ tlin, float* __restrict__ out)
{
    __shared__ unsigned short T[32 * 40];
    __shared__ float red[4][192];
    const int bid = blockIdx.x;
    const int t = threadIdx.x;

    if (bid == 3064) {
        const float4 z = {0.f, 0.f, 0.f, 0.f};
        ((float4*)hlin)[t] = z; ((float4*)hlin)[256 + t] = z;
        ((float4*)tlin)[t] = z; ((float4*)tlin)[256 + t] = z;
        if (t == 0) out[0] = 0.f;
        return;
    }

    if (bid >= 3040) {
        // ---- embc: per-(label, col) folded bias table
        const int eb = bid - 3040;           // 0..23
        const int tc = t & 63;
        const int kg = t >> 6;               // 0..3 k-group
        const int n = eb * 64 + tc;          // global col 0..1535
        const float* W = (n < 768) ? hW1 : tW1;
        const int cc = (n < 768) ? n : n - 768;
        float a0 = 0.f, a1 = 0.f, a2 = 0.f;
        const int kbeg = kg * 192;
        #pragma unroll 8
        for (int k = kbeg; k < kbeg + 192; ++k) {
            const float w = W[(size_t)(768 + k) * 768 + cc];
            a0 += emb[k] * w;
            a1 += emb[768 + k] * w;
            a2 += emb[1536 + k] * w;
        }
        red[kg][0 * 64 + tc] = a0;
        red[kg][1 * 64 + tc] = a1;
        red[kg][2 * 64 + tc] = a2;
        __syncthreads();
        if (kg == 0) {
            const float b = (n < 768) ? hb1[n] : tb1[n - 768];
            #pragma unroll
            for (int l = 0; l < 3; ++l) {
                embc[l * 1536 + n] = b + red[0][l * 64 + tc] + red[1][l * 64 + tc]
                                       + red[2][l * 64 + tc] + red[3][l * 64 + tc];
            }
        }
        return;
    }

    if (bid >= 2016) {
        // ---- gather hidden[b, ent_start[m]] as bf16 (768 cols)
        const int m = bid - 2016;            // 0..1023
        if (t >= 96) return;
        const int b = m >> 9;
        const int idx = ent_start[m];
        const float4* s = (const float4*)(hidden + (size_t)(b * LL + idx) * HH);
        const float4 v0 = s[2 * t];
        const float4 v1 = s[2 * t + 1];
        u16x8 o;
        o[0] = f2bf(v0.x); o[1] = f2bf(v0.y); o[2] = f2bf(v0.z); o[3] = f2bf(v0.w);
        o[4] = f2bf(v1.x); o[5] = f2bf(v1.y); o[6] = f2bf(v1.z); o[7] = f2bf(v1.w);
        *(u16x8*)(Hbf + (size_t)m * 768 + 8 * t) = o;
        return;
    }

    // ---- weight transpose (32x32 tile per block)
    const float* src; unsigned short* dst; int K, N, tile;
    if (bid < 576)       { src = hW1;            dst = W1ht; K = 768; N = 768; tile = bid; }
    else if (bid < 1152) { src = tW1;            dst = W1tt; K = 768; N = 768; tile = bid - 576; }
    else if (bid < 1440) { src = hW2;            dst = W2ht; K = 768; N = 384; tile = bid - 1152; }
    else if (bid < 1728) { src = tW2;            dst = W2tt; K = 768; N = 384; tile = bid - 1440; }
    else if (bid < 1872) { src = bilW;           dst = bW0t; K = 384; N = 384; tile = bid - 1728; }
    else                 { src = bilW + 384*384; dst = bW1t; K = 384; N = 384; tile = bid - 1872; }
    const int tn = N >> 5;
    const int n0 = (tile % tn) * 32;
    const int k0 = (tile / tn) * 32;

    const int r  = t >> 3;           // 0..31 (k within tile)
    const int c4 = (t & 7) * 4;      // 0..28 (n within tile)
    const float4 g = *(const float4*)(src + (size_t)(k0 + r) * N + n0 + c4);
    T[(c4 + 0) * 40 + r] = f2bf(g.x);
    T[(c4 + 1) * 40 + r] = f2bf(g.y);
    T[(c4 + 2) * 40 + r] = f2bf(g.z);
    T[(c4 + 3) * 40 + r] = f2bf(g.w);
    __syncthreads();
    const int n  = t >> 3;           // 0..31
    const int k4 = (t & 7) * 4;      // 0..28
    *(ushort4*)(dst + (size_t)(n0 + n) * K + k0 + k4) = *(ushort4*)&T[n * 40 + k4];
}

// ---------------------------------------------------------------------------
// bf16 MFMA GEMM. 64x64 tile, 256 threads (4 waves, 2x2), 16x16x32 MFMA.
// K_STEP=64, double-buffered LDS, ONE raw s_barrier per K-step (no vmcnt
// drain: prefetch loads for step k+1 stay in flight across the barrier; the
// compiler's vmcnt wait lands at the ds_write, after the MFMA cluster).
// A: [M][lda] bf16 row-major; half 1 (n0>=Nh) uses k-offset aoff1 + Bt1.
// EB:  per-(row-label, col) bias table embc[3][1536] (layer1 emb folding).
// LIN: epilogue also reduces v·linW[col] per row (16-lane shfl reduce)
//      and atomicAdds into hlin/tlin (fused lin_proj).
// ---------------------------------------------------------------------------
template<bool RELU, bool BIAS, bool EB, bool LIN>
__global__ __launch_bounds__(256) void gemm_mfma(
    const unsigned short* __restrict__ A, int lda, int aoff1,
    const unsigned short* __restrict__ Bt0, const unsigned short* __restrict__ Bt1,
    int ldb, int Nh,
    const float* __restrict__ bias0, const float* __restrict__ bias1,
    const float* __restrict__ embc, const int* __restrict__ labels,
    const float* __restrict__ linW, float* __restrict__ hlin, float* __restrict__ tlin,
    int K, unsigned short* __restrict__ Cb, int ldc)
{
    __shared__ __align__(16) unsigned short As[2][64 * 72];
    __shared__ __align__(16) unsigned short Bs[2][64 * 72];

    const int tid = threadIdx.x;
    const int n0 = blockIdx.x * 64;
    const int m0 = blockIdx.y * 64;
    const int hf = (n0 >= Nh) ? 1 : 0;
    const unsigned short* Bt = hf ? Bt1 : Bt0;
    const int nc0 = n0 - (hf ? Nh : 0);
    const int aoff = hf ? aoff1 : 0;

    const int sr = tid >> 2;            // 0..63
    const int sk = (tid & 3) * 16;      // 0,16,32,48

    const unsigned short* Ap = A + (size_t)(m0 + sr) * lda + aoff + sk;
    const unsigned short* Bp = Bt + (size_t)(nc0 + sr) * ldb + sk;

    const int lane = tid & 63;
    const int wave = tid >> 6;
    const int wm = (wave & 1) * 32;
    const int wn = (wave >> 1) * 32;
    const int l15 = lane & 15;
    const int quad = lane >> 4;

    f32x4 acc00 = {}, acc01 = {}, acc10 = {}, acc11 = {};

    // prologue: K-step 0 -> regs -> LDS buf0
    u16x8 a0v = *(const u16x8*)(Ap);
    u16x8 a1v = *(const u16x8*)(Ap + 8);
    u16x8 b0v = *(const u16x8*)(Bp);
    u16x8 b1v = *(const u16x8*)(Bp + 8);
    const int swo = sr * 72 + sk;
    *(u16x8*)&As[0][swo] = a0v; *(u16x8*)&As[0][swo + 8] = a1v;
    *(u16x8*)&Bs[0][swo] = b0v; *(u16x8*)&Bs[0][swo + 8] = b1v;

    const int NT = K >> 6;
    const int aro = quad * 8;
    int cur = 0;
    for (int it = 0; it < NT; ++it) {
        if (it + 1 < NT) {              // issue next step's loads (in flight)
            const int ko = (it + 1) * 64;
            a0v = *(const u16x8*)(Ap + ko); a1v = *(const u16x8*)(Ap + ko + 8);
            b0v = *(const u16x8*)(Bp + ko); b1v = *(const u16x8*)(Bp + ko + 8);
        }
        asm volatile("s_waitcnt lgkmcnt(0)" ::: "memory");
        __builtin_amdgcn_s_barrier();
        __builtin_amdgcn_sched_barrier(0);
        const unsigned short* Ac = As[cur];
        const unsigned short* Bc = Bs[cur];
        const bf16x8 fa0 = *(const bf16x8*)&Ac[(wm + l15) * 72 + aro];
        const bf16x8 fa1 = *(const bf16x8*)&Ac[(wm + 16 + l15) * 72 + aro];
        const bf16x8 fb0 = *(const bf16x8*)&Bc[(wn + l15) * 72 + aro];
        const bf16x8 fb1 = *(const bf16x8*)&Bc[(wn + 16 + l15) * 72 + aro];
        const bf16x8 ga0 = *(const bf16x8*)&Ac[(wm + l15) * 72 + aro + 32];
        const bf16x8 ga1 = *(const bf16x8*)&Ac[(wm + 16 + l15) * 72 + aro + 32];
        const bf16x8 gb0 = *(const bf16x8*)&Bc[(wn + l15) * 72 + aro + 32];
        const bf16x8 gb1 = *(const bf16x8*)&Bc[(wn + 16 + l15) * 72 + aro + 32];
        acc00 = __builtin_amdgcn_mfma_f32_16x16x32_bf16(fa0, fb0, acc00, 0, 0, 0);
        acc01 = __builtin_amdgcn_mfma_f32_16x16x32_bf16(fa0, fb1, acc01, 0, 0, 0);
        acc10 = __builtin_amdgcn_mfma_f32_16x16x32_bf16(fa1, fb0, acc10, 0, 0, 0);
        acc11 = __builtin_amdgcn_mfma_f32_16x16x32_bf16(fa1, fb1, acc11, 0, 0, 0);
        acc00 = __builtin_amdgcn_mfma_f32_16x16x32_bf16(ga0, gb0, acc00, 0, 0, 0);
        acc01 = __builtin_amdgcn_mfma_f32_16x16x32_bf16(ga0, gb1, acc01, 0, 0, 0);
        acc10 = __builtin_amdgcn_mfma_f32_16x16x32_bf16(ga1, gb0, acc10, 0, 0, 0);
        acc11 = __builtin_amdgcn_mfma_f32_16x16x32_bf16(ga1, gb1, acc11, 0, 0, 0);
        if (it + 1 < NT) {
            unsigned short* Aw = As[cur ^ 1];
            unsigned short* Bw = Bs[cur ^ 1];
            *(u16x8*)&Aw[swo] = a0v; *(u16x8*)&Aw[swo + 8] = a1v;
            *(u16x8*)&Bw[swo] = b0v; *(u16x8*)&Bw[swo + 8] = b1v;
        }
        cur ^= 1;
    }

    // epilogue: C/D layout col=lane&15, row=quad*4+reg
    float bias_v0 = 0.f, bias_v1 = 0.f;
    if (BIAS) {
        const float* bb = hf ? bias1 : bias0;
        bias_v0 = bb[nc0 + wn + l15];
        bias_v1 = bb[nc0 + wn + 16 + l15];
    }
    const int col0 = n0 + wn + l15;
    const int col1 = col0 + 16;
    float2 lw0 = {0.f, 0.f}, lw1 = {0.f, 0.f};
    float* lout = nullptr;
    if (LIN) {
        lw0 = ((const float2*)linW)[col0];
        lw1 = ((const float2*)linW)[col1];
        lout = hf ? tlin : hlin;
    }
    const f32x4 accs[2][2] = {{acc00, acc01}, {acc10, acc11}};
    #pragma unroll
    for (int mi = 0; mi < 2; ++mi) {
        #pragma unroll
        for (int r = 0; r < 4; ++r) {
            const int row = m0 + wm + mi * 16 + quad * 4 + r;
            float v0 = accs[mi][0][r];
            float v1 = accs[mi][1][r];
            if (BIAS) { v0 += bias_v0; v1 += bias_v1; }
            if (EB) {
                const int lab = labels[row];
                v0 += embc[lab * 1536 + col0];
                v1 += embc[lab * 1536 + col1];
            }
            if (RELU) { v0 = fmaxf(v0, 0.f); v1 = fmaxf(v1, 0.f); }
            Cb[(size_t)row * ldc + col0] = f2bf(v0);
            Cb[(size_t)row * ldc + col1] = f2bf(v1);
            if (LIN) {
                float s0 = v0 * lw0.x + v1 * lw1.x;
                float s1 = v0 * lw0.y + v1 * lw1.y;
                #pragma unroll
                for (int o = 8; o >= 1; o >>= 1) {
                    s0 += __shfl_xor(s0, o, 64);
                    s1 += __shfl_xor(s1, o, 64);
                }
                if (l15 == 0) {
                    atomicAdd(&lout[2 * row],     s0);
                    atomicAdd(&lout[2 * row + 1], s1);
                }
            }
        }
    }
}

// ---------------------------------------------------------------------------
// Direct per-relation bilinear score + CE (replaces score-table GEMM +
// gather). One wave per relation, 8 relations per wave. Lanes split the
// 384-dim dot over hW (both o-planes) and tails; both operands L2-resident.
// ---------------------------------------------------------------------------
__global__ __launch_bounds__(256) void rel_score(
    const unsigned short* __restrict__ hWbf, const unsigned short* __restrict__ HTbf,
    const float* __restrict__ hlin, const float* __restrict__ tlin,
    const float* __restrict__ lin_b,
    const int* __restrict__ rel_head, const int* __restrict__ rel_tail,
    const int* __restrict__ rel_label,
    float* __restrict__ out)
{
    const int tid = threadIdx.x;
    const int lane = tid & 63;
    const int wave = tid >> 6;
    const float lb0 = lin_b[0], lb1 = lin_b[1];
    const int base = (blockIdx.x * 4 + wave) * 8;
    float ce_acc = 0.f;
    for (int r = 0; r < 8; ++r) {
        const int i = base + r;                 // relation 0..65535
        const int b = i >> 15;
        const int h = rel_head[i];
        const int t = rel_tail[i];
        const int mh = (b << 9) + h;
        const int mt = (b << 9) + t;
        const unsigned short* hw = hWbf + (size_t)mh * 768;
        const unsigned short* tp = HTbf + (size_t)mt * 768 + 384;
        float a0 = 0.f, a1 = 0.f;
        #pragma unroll
        for (int j = 0; j < 6; ++j) {
            const int d = j * 64 + lane;
            const float tv = bf2f(tp[d]);
            a0 += bf2f(hw[d])       * tv;
            a1 += bf2f(hw[384 + d]) * tv;
        }
        #pragma unroll
        for (int o = 32; o >= 1; o >>= 1) {
            a0 += __shfl_xor(a0, o, 64);
            a1 += __shfl_xor(a1, o, 64);
        }
        if (lane == 0) {
            const float2 hl = ((const float2*)hlin)[mh];
            const float2 tl = ((const float2*)tlin)[mt];
            const float z0 = a0 + hl.x + tl.x + lb0;
            const float z1 = a1 + hl.y + tl.y + lb1;
            out[1 + 2 * (size_t)i] = z0;
            out[2 + 2 * (size_t)i] = z1;
            const float mx = fmaxf(z0, z1);
            const float mn = fminf(z0, z1);
            const int lab = rel_label[i];
            ce_acc += mx + log1pf(expf(mn - mx)) - (lab ? z1 : z0);
        }
    }
    __shared__ float wsum[4];
    if (lane == 0) wsum[wave] = ce_acc;
    __syncthreads();
    if (tid == 0)
        atomicAdd(out, (wsum[0] + wsum[1] + wsum[2] + wsum[3]) * (1.0f / (float)RR));
}

// ---------------------------------------------------------------------------
extern "C" void kernel_launch(void* const* d_in, const int* in_sizes, int n_in,
                              void* d_out, int out_size, void* d_ws, size_t ws_size,
                              hipStream_t stream) {
    const float* hidden    = (const float*)d_in[0];
    const int*   ent_start = (const int*)d_in[1];
    const int*   ent_label = (const int*)d_in[2];
    const int*   rel_head  = (const int*)d_in[3];
    const int*   rel_tail  = (const int*)d_in[4];
    const int*   rel_label = (const int*)d_in[5];
    const float* emb       = (const float*)d_in[6];
    const float* head_W1   = (const float*)d_in[7];
    const float* head_b1   = (const float*)d_in[8];
    const float* head_W2   = (const float*)d_in[9];
    const float* head_b2   = (const float*)d_in[10];
    const float* tail_W1   = (const float*)d_in[11];
    const float* tail_b1   = (const float*)d_in[12];
    const float* tail_W2   = (const float*)d_in[13];
    const float* tail_b2   = (const float*)d_in[14];
    const float* bil_W     = (const float*)d_in[15];
    const float* lin_W     = (const float*)d_in[16];
    const float* lin_b     = (const float*)d_in[17];
    float* out = (float*)d_out;

    // Workspace carve-up (256B-aligned chunks)
    char* w = (char*)d_ws;
    auto carve = [&](size_t bytes) {
        char* p = w; w += (bytes + 255) & ~(size_t)255; return p;
    };
    unsigned short* Hbf  = (unsigned short*)carve((size_t)MM * 768 * 2);
    unsigned short* Y1bf = (unsigned short*)carve((size_t)MM * 1536 * 2);
    unsigned short* HTbf = (unsigned short*)carve((size_t)MM * 768 * 2);
    unsigned short* hWbf = (unsigned short*)carve((size_t)MM * 768 * 2);
    unsigned short* W1ht = (unsigned short*)carve((size_t)768 * 768 * 2);
    unsigned short* W1tt = (unsigned short*)carve((size_t)768 * 768 * 2);
    unsigned short* W2ht = (unsigned short*)carve((size_t)384 * 768 * 2);
    unsigned short* W2tt = (unsigned short*)carve((size_t)384 * 768 * 2);
    unsigned short* bW0t = (unsigned short*)carve((size_t)384 * 384 * 2);
    unsigned short* bW1t = (unsigned short*)carve((size_t)384 * 384 * 2);
    float*          embc = (float*)carve((size_t)3 * 1536 * 4);
    float*          hlin = (float*)carve(2048 * 4);
    float*          tlin = (float*)carve(2048 * 4);

    // 1) weight transpose->bf16 + hidden gather->bf16 + embc fold + zeroing
    prep<<<3065, 256, 0, stream>>>(
        head_W1, tail_W1, head_W2, tail_W2, bil_W,
        W1ht, W1tt, W2ht, W2tt, bW0t, bW1t,
        hidden, ent_start, ent_label, emb, head_b1, tail_b1, Hbf, embc,
        hlin, tlin, out);

    // 2) layer1: Y1 = relu(Hbf @ [W1h'|W1t'] + embc[lab]), N=1536 (Nh=768), K=768
    gemm_mfma<true, false, true, false><<<dim3(24, 16), 256, 0, stream>>>(
        Hbf, 768, 0, W1ht, W1tt, 768, 768, nullptr, nullptr, embc, ent_label,
        nullptr, nullptr, nullptr, 768, Y1bf, 1536);

    // 3) layer2: HTbf = relu(Y1 @ [W2h|W2t] + b2), N=768 (Nh=384), K=768,
    //    tail half reads Y1 cols 768..; epilogue fuses lin_proj via atomics
    gemm_mfma<true, true, false, true><<<dim3(12, 16), 256, 0, stream>>>(
        Y1bf, 1536, 768, W2ht, W2tt, 768, 384, head_b2, tail_b2, nullptr, nullptr,
        lin_W, hlin, tlin, 768, HTbf, 768);

    // 4) bilinear left product: hWbf = heads @ bil_W[o], N=768 (Nh=384), K=384
    gemm_mfma<false, false, false, false><<<dim3(12, 16), 256, 0, stream>>>(
        HTbf, 768, 0, bW0t, bW1t, 384, 384, nullptr, nullptr, nullptr, nullptr,
        nullptr, nullptr, nullptr, 384, hWbf, 768);

    // 5) direct per-relation score + CE + fused loss reduction
    rel_score<<<2048, 256, 0, stream>>>(hWbf, HTbf, hlin, tlin, lin_b,
                                        rel_head, rel_tail, rel_label, out);
}

// Round 5
// 147.422 us; speedup vs baseline: 2.6127x; 1.1501x over previous
//
#include <hip/hip_runtime.h>
#include <math.h>

// Problem constants
#define BB 2
#define LL 512
#define HH 768
#define EE 512
#define RR 32768
#define H2 384
#define MM 1024   // B*E entity rows

typedef __attribute__((ext_vector_type(8))) short     bf16x8;  // MFMA A/B frag
typedef __attribute__((ext_vector_type(4))) float     f32x4;   // MFMA C/D frag
typedef __attribute__((ext_vector_type(8))) unsigned short u16x8;

#define BUFE (64 * 136)   // one LDS buffer: 64 rows x (128+8) bf16

__device__ __forceinline__ unsigned short f2bf(float f) {
    unsigned int u = __float_as_uint(f);
    u = (u + 0x7FFFu + ((u >> 16) & 1u)) >> 16;   // round-to-nearest-even
    return (unsigned short)u;
}

// ---------------------------------------------------------------------------
// 32x32 weight transpose tile: [K][N] fp32 -> [N][K] bf16. T = 32*40 ushorts.
// ---------------------------------------------------------------------------
__device__ __forceinline__ void wtrans(const float* __restrict__ src,
                                       unsigned short* __restrict__ dst,
                                       int K, int N, int tile, unsigned short* T)
{
    const int t = threadIdx.x;
    const int tn = N >> 5;
    const int n0 = (tile % tn) * 32;
    const int k0 = (tile / tn) * 32;
    const int r  = t >> 3;           // 0..31 (k within tile)
    const int c4 = (t & 7) * 4;      // 0..28 (n within tile)
    const float4 g = *(const float4*)(src + (size_t)(k0 + r) * N + n0 + c4);
    T[(c4 + 0) * 40 + r] = f2bf(g.x);
    T[(c4 + 1) * 40 + r] = f2bf(g.y);
    T[(c4 + 2) * 40 + r] = f2bf(g.z);
    T[(c4 + 3) * 40 + r] = f2bf(g.w);
    __syncthreads();
    const int n  = t >> 3;           // 0..31
    const int k4 = (t & 7) * 4;      // 0..28
    *(ushort4*)(dst + (size_t)(n0 + n) * K + k0 + k4) = *(ushort4*)&T[n * 40 + k4];
}

// ---------------------------------------------------------------------------
// prep:
//   [0,576)     W1 head top-half transpose -> W1ht
//   [576,1152)  W1 tail top-half transpose -> W1tt
//   [1152,2176) gather hidden[b, ent_start] -> Hbf bf16 [1024][768]
//   [2176,2200) embc[l][n] = b1[n] + sum_k emb[l][k]*W1[768+k][n]
//   2200        zero hlin/tlin accumulators + out[0]
// (W2/bil transposes moved into the gemm1 launch — they don't gate gemm1.)
// ---------------------------------------------------------------------------
__global__ __launch_bounds__(256) void prep(
    const float* __restrict__ hW1, const float* __restrict__ tW1,
    unsigned short* __restrict__ W1ht, unsigned short* __restrict__ W1tt,
    const float* __restrict__ hidden, const int* __restrict__ ent_start,
    const float* __restrict__ emb,
    const float* __restrict__ hb1, const float* __restrict__ tb1,
    unsigned short* __restrict__ Hbf, float* __restrict__ embc,
    float* __restrict__ hlin, float* __restrict__ tlin, float* __restrict__ out)
{
    __shared__ unsigned short T[32 * 40];
    __shared__ float red[4][192];
    const int bid = blockIdx.x;
    const int t = threadIdx.x;

    if (bid == 2200) {
        const float4 z = {0.f, 0.f, 0.f, 0.f};
        ((float4*)hlin)[t] = z; ((float4*)hlin)[256 + t] = z;
        ((float4*)tlin)[t] = z; ((float4*)tlin)[256 + t] = z;
        if (t == 0) out[0] = 0.f;
        return;
    }

    if (bid >= 2176) {
        // ---- embc: per-(label, col) folded bias table
        const int eb = bid - 2176;           // 0..23
        const int tc = t & 63;
        const int kg = t >> 6;               // 0..3 k-group
        const int n = eb * 64 + tc;          // global col 0..1535
        const float* W = (n < 768) ? hW1 : tW1;
        const int cc = (n < 768) ? n : n - 768;
        float a0 = 0.f, a1 = 0.f, a2 = 0.f;
        const int kbeg = kg * 192;
        #pragma unroll 8
        for (int k = kbeg; k < kbeg + 192; ++k) {
            const float w = W[(size_t)(768 + k) * 768 + cc];
            a0 += emb[k] * w;
            a1 += emb[768 + k] * w;
            a2 += emb[1536 + k] * w;
        }
        red[kg][0 * 64 + tc] = a0;
        red[kg][1 * 64 + tc] = a1;
        red[kg][2 * 64 + tc] = a2;
        __syncthreads();
        if (kg == 0) {
            const float b = (n < 768) ? hb1[n] : tb1[n - 768];
            #pragma unroll
            for (int l = 0; l < 3; ++l) {
                embc[l * 1536 + n] = b + red[0][l * 64 + tc] + red[1][l * 64 + tc]
                                       + red[2][l * 64 + tc] + red[3][l * 64 + tc];
            }
        }
        return;
    }

    if (bid >= 1152) {
        // ---- gather hidden[b, ent_start[m]] as bf16 (768 cols)
        const int m = bid - 1152;            // 0..1023
        if (t >= 96) return;
        const int b = m >> 9;
        const int idx = ent_start[m];
        const float4* s = (const float4*)(hidden + (size_t)(b * LL + idx) * HH);
        const float4 v0 = s[2 * t];
        const float4 v1 = s[2 * t + 1];
        u16x8 o;
        o[0] = f2bf(v0.x); o[1] = f2bf(v0.y); o[2] = f2bf(v0.z); o[3] = f2bf(v0.w);
        o[4] = f2bf(v1.x); o[5] = f2bf(v1.y); o[6] = f2bf(v1.z); o[7] = f2bf(v1.w);
        *(u16x8*)(Hbf + (size_t)m * 768 + 8 * t) = o;
        return;
    }

    // ---- W1 transposes (top halves only; bottom folded into embc)
    if (bid < 576) wtrans(hW1, W1ht, 768, 768, bid, T);
    else           wtrans(tW1, W1tt, 768, 768, bid - 576, T);
}

// ---------------------------------------------------------------------------
// bf16 MFMA GEMM body. 64x64 tile, 256 threads (4 waves, 2x2), 16x16x32 MFMA.
// K_STEP=128, double-buffered LDS, ONE raw s_barrier per K-step (no vmcnt
// drain: prefetch loads for step k+1 stay in flight across the barrier; the
// compiler's vmcnt wait lands at the ds_write, after the 16-MFMA cluster).
// A: [M][lda] bf16 row-major; half 1 (n0>=Nh) uses k-offset aoff1 + Bt1.
// B: transposed [*][ldb]; +((m0>>9)*bt_mrow) row offset for the batch-blocked
//    score GEMM.
// EB:  per-(row-label, col) bias table embc[3][1536] (layer1 emb folding).
// O2:  interleaved fp32 output col' = 2*(col within half) + half  (Stab).
// LIN: epilogue reduces v·linW[col] per row (16-lane shfl) -> atomicAdd
//      into hlin/tlin (fused lin_proj).
// ---------------------------------------------------------------------------
template<bool RELU, bool BIAS, bool EB, bool WF32, bool WBF16, bool O2, bool LIN>
__device__ __forceinline__ void gemm_body(
    int tile, int nx,
    const unsigned short* __restrict__ A, int lda, int aoff1,
    const unsigned short* __restrict__ Bt0, const unsigned short* __restrict__ Bt1,
    int ldb, int bt_mrow, int Nh,
    const float* __restrict__ bias0, const float* __restrict__ bias1,
    const float* __restrict__ embc, const int* __restrict__ labels,
    const float* __restrict__ linW, float* __restrict__ hlin, float* __restrict__ tlin,
    int K, float* __restrict__ Cf, unsigned short* __restrict__ Cb, int ldc,
    unsigned short* As, unsigned short* Bs)
{
    const int tid = threadIdx.x;
    const int n0 = (tile % nx) * 64;
    const int m0 = (tile / nx) * 64;
    const int hf = (n0 >= Nh) ? 1 : 0;
    const unsigned short* Bt = hf ? Bt1 : Bt0;
    const int nc0 = n0 - (hf ? Nh : 0);
    const int aoff = hf ? aoff1 : 0;

    // staging: thread t covers row sr, 32 bf16 at k-offset sk (4 x u16x8)
    const int sr = tid >> 2;            // 0..63
    const int sk = (tid & 3) * 32;      // 0,32,64,96

    const unsigned short* Ap = A + (size_t)(m0 + sr) * lda + aoff + sk;
    const unsigned short* Bp = Bt + (size_t)((m0 >> 9) * bt_mrow + nc0 + sr) * ldb + sk;

    const int lane = tid & 63;
    const int wave = tid >> 6;
    const int wm = (wave & 1) * 32;
    const int wn = (wave >> 1) * 32;
    const int l15 = lane & 15;
    const int quad = lane >> 4;

    f32x4 acc00 = {}, acc01 = {}, acc10 = {}, acc11 = {};

    // prologue: K-step 0 -> regs -> LDS buf0
    u16x8 av0 = *(const u16x8*)(Ap);      u16x8 av1 = *(const u16x8*)(Ap + 8);
    u16x8 av2 = *(const u16x8*)(Ap + 16); u16x8 av3 = *(const u16x8*)(Ap + 24);
    u16x8 bv0 = *(const u16x8*)(Bp);      u16x8 bv1 = *(const u16x8*)(Bp + 8);
    u16x8 bv2 = *(const u16x8*)(Bp + 16); u16x8 bv3 = *(const u16x8*)(Bp + 24);
    const int swo = sr * 136 + sk;
    *(u16x8*)&As[swo] = av0;      *(u16x8*)&As[swo + 8] = av1;
    *(u16x8*)&As[swo + 16] = av2; *(u16x8*)&As[swo + 24] = av3;
    *(u16x8*)&Bs[swo] = bv0;      *(u16x8*)&Bs[swo + 8] = bv1;
    *(u16x8*)&Bs[swo + 16] = bv2; *(u16x8*)&Bs[swo + 24] = bv3;

    const int NT = K >> 7;              // K / 128
    const int aro = quad * 8;
    int cur = 0;
    for (int it = 0; it < NT; ++it) {
        if (it + 1 < NT) {              // issue next step's loads (in flight)
            const int ko = (it + 1) * 128;
            av0 = *(const u16x8*)(Ap + ko);      av1 = *(const u16x8*)(Ap + ko + 8);
            av2 = *(const u16x8*)(Ap + ko + 16); av3 = *(const u16x8*)(Ap + ko + 24);
            bv0 = *(const u16x8*)(Bp + ko);      bv1 = *(const u16x8*)(Bp + ko + 8);
            bv2 = *(const u16x8*)(Bp + ko + 16); bv3 = *(const u16x8*)(Bp + ko + 24);
        }
        asm volatile("s_waitcnt lgkmcnt(0)" ::: "memory");  // my ds ops done
        __builtin_amdgcn_s_barrier();                        // no vmcnt drain
        __builtin_amdgcn_sched_barrier(0);
        const unsigned short* Ac = As + cur * BUFE;
        const unsigned short* Bc = Bs + cur * BUFE;
        #pragma unroll
        for (int s = 0; s < 4; ++s) {
            const int ks = s * 32 + aro;
            const bf16x8 fa0 = *(const bf16x8*)&Ac[(wm + l15) * 136 + ks];
            const bf16x8 fa1 = *(const bf16x8*)&Ac[(wm + 16 + l15) * 136 + ks];
            const bf16x8 fb0 = *(const bf16x8*)&Bc[(wn + l15) * 136 + ks];
            const bf16x8 fb1 = *(const bf16x8*)&Bc[(wn + 16 + l15) * 136 + ks];
            acc00 = __builtin_amdgcn_mfma_f32_16x16x32_bf16(fa0, fb0, acc00, 0, 0, 0);
            acc01 = __builtin_amdgcn_mfma_f32_16x16x32_bf16(fa0, fb1, acc01, 0, 0, 0);
            acc10 = __builtin_amdgcn_mfma_f32_16x16x32_bf16(fa1, fb0, acc10, 0, 0, 0);
            acc11 = __builtin_amdgcn_mfma_f32_16x16x32_bf16(fa1, fb1, acc11, 0, 0, 0);
        }
        if (it + 1 < NT) {
            unsigned short* Aw = As + (cur ^ 1) * BUFE;
            unsigned short* Bw = Bs + (cur ^ 1) * BUFE;
            *(u16x8*)&Aw[swo] = av0;      *(u16x8*)&Aw[swo + 8] = av1;
            *(u16x8*)&Aw[swo + 16] = av2; *(u16x8*)&Aw[swo + 24] = av3;
            *(u16x8*)&Bw[swo] = bv0;      *(u16x8*)&Bw[swo + 8] = bv1;
            *(u16x8*)&Bw[swo + 16] = bv2; *(u16x8*)&Bw[swo + 24] = bv3;
        }
        cur ^= 1;
    }

    // epilogue: C/D layout col=lane&15, row=quad*4+reg
    float bias_v0 = 0.f, bias_v1 = 0.f;
    if (BIAS) {
        const float* bb = hf ? bias1 : bias0;
        bias_v0 = bb[nc0 + wn + l15];
        bias_v1 = bb[nc0 + wn + 16 + l15];
    }
    const int col0 = n0 + wn + l15;
    const int col1 = col0 + 16;
    int colw0 = col0, colw1 = col1;
    if (O2) {
        colw0 = 2 * (nc0 + wn + l15) + hf;
        colw1 = 2 * (nc0 + wn + 16 + l15) + hf;
    }
    float2 lw0 = {0.f, 0.f}, lw1 = {0.f, 0.f};
    float* lout = nullptr;
    if (LIN) {
        lw0 = ((const float2*)linW)[col0];
        lw1 = ((const float2*)linW)[col1];
        lout = hf ? tlin : hlin;
    }
    const f32x4 accs[2][2] = {{acc00, acc01}, {acc10, acc11}};
    #pragma unroll
    for (int mi = 0; mi < 2; ++mi) {
        #pragma unroll
        for (int r = 0; r < 4; ++r) {
            const int row = m0 + wm + mi * 16 + quad * 4 + r;
            float v0 = accs[mi][0][r];
            float v1 = accs[mi][1][r];
            if (BIAS) { v0 += bias_v0; v1 += bias_v1; }
            if (EB) {
                const int lab = labels[row];
                v0 += embc[lab * 1536 + col0];
                v1 += embc[lab * 1536 + col1];
            }
            if (RELU) { v0 = fmaxf(v0, 0.f); v1 = fmaxf(v1, 0.f); }
            if (WF32) {
                Cf[(size_t)row * ldc + colw0] = v0;
                Cf[(size_t)row * ldc + colw1] = v1;
            }
            if (WBF16) {
                Cb[(size_t)row * ldc + colw0] = f2bf(v0);
                Cb[(size_t)row * ldc + colw1] = f2bf(v1);
            }
            if (LIN) {
                float s0 = v0 * lw0.x + v1 * lw1.x;
                float s1 = v0 * lw0.y + v1 * lw1.y;
                #pragma unroll
                for (int o = 8; o >= 1; o >>= 1) {
                    s0 += __shfl_xor(s0, o, 64);
                    s1 += __shfl_xor(s1, o, 64);
                }
                if (l15 == 0) {
                    atomicAdd(&lout[2 * row],     s0);
                    atomicAdd(&lout[2 * row + 1], s1);
                }
            }
        }
    }
}

// Generic GEMM kernel (stages 2-4), 2-D grid.
template<bool RELU, bool BIAS, bool EB, bool WF32, bool WBF16, bool O2, bool LIN>
__global__ __launch_bounds__(256) void gemm_mfma(
    const unsigned short* __restrict__ A, int lda, int aoff1,
    const unsigned short* __restrict__ Bt0, const unsigned short* __restrict__ Bt1,
    int ldb, int bt_mrow, int Nh,
    const float* __restrict__ bias0, const float* __restrict__ bias1,
    const float* __restrict__ embc, const int* __restrict__ labels,
    const float* __restrict__ linW, float* __restrict__ hlin, float* __restrict__ tlin,
    int K, float* __restrict__ Cf, unsigned short* __restrict__ Cb, int ldc)
{
    __shared__ __align__(16) unsigned short As[2 * BUFE];
    __shared__ __align__(16) unsigned short Bs[2 * BUFE];
    gemm_body<RELU, BIAS, EB, WF32, WBF16, O2, LIN>(
        blockIdx.y * gridDim.x + blockIdx.x, gridDim.x,
        A, lda, aoff1, Bt0, Bt1, ldb, bt_mrow, Nh,
        bias0, bias1, embc, labels, linW, hlin, tlin,
        K, Cf, Cb, ldc, As, Bs);
}

// ---------------------------------------------------------------------------
// gemm1 + overlapped W2/bil transposes: blocks [0,384) = layer1 tiles,
// blocks [384,1248) = weight transposes that only gemm2/3/4 consume (safe:
// they complete before this launch finishes, and consumers launch after).
// ---------------------------------------------------------------------------
__global__ __launch_bounds__(256) void gemm1_plus(
    const unsigned short* __restrict__ Hbf,
    const unsigned short* __restrict__ W1ht, const unsigned short* __restrict__ W1tt,
    const float* __restrict__ embc, const int* __restrict__ ent_label,
    unsigned short* __restrict__ Y1bf,
    const float* __restrict__ hW2, const float* __restrict__ tW2,
    const float* __restrict__ bilW,
    unsigned short* __restrict__ W2ht, unsigned short* __restrict__ W2tt,
    unsigned short* __restrict__ bW0t, unsigned short* __restrict__ bW1t)
{
    __shared__ __align__(16) unsigned short As[2 * BUFE];
    __shared__ __align__(16) unsigned short Bs[2 * BUFE];
    const int bid = blockIdx.x;
    if (bid >= 384) {
        const int task = bid - 384;
        if (task < 288)      wtrans(hW2, W2ht, 768, 384, task, As);
        else if (task < 576) wtrans(tW2, W2tt, 768, 384, task - 288, As);
        else if (task < 720) wtrans(bilW, bW0t, 384, 384, task - 576, As);
        else                 wtrans(bilW + 384 * 384, bW1t, 384, 384, task - 720, As);
        return;
    }
    gemm_body<true, false, true, false, true, false, false>(
        bid, 24, Hbf, 768, 0, W1ht, W1tt, 768, 0, 768,
        nullptr, nullptr, embc, ent_label, nullptr, nullptr, nullptr,
        768, nullptr, Y1bf, 1536, As, Bs);
}

// ---------------------------------------------------------------------------
// Per-relation gather from the score table + CE reduction (fused loss).
// One thread per relation. Stab interleaved: Stab[mh][2*t + o].
// ---------------------------------------------------------------------------
__global__ __launch_bounds__(256) void rel_gather(
    const float* __restrict__ Stab,
    const float* __restrict__ hlin, const float* __restrict__ tlin,
    const float* __restrict__ lin_b,
    const int* __restrict__ rel_head, const int* __restrict__ rel_tail,
    const int* __restrict__ rel_label,
    float* __restrict__ out)
{
    const int tid = threadIdx.x;
    const int i = blockIdx.x * 256 + tid;       // relation 0..65535
    const int b = i >> 15;
    const int h = rel_head[i];
    const int t = rel_tail[i];
    const int lab = rel_label[i];
    const int mh = (b << 9) + h;
    const int mt = (b << 9) + t;

    const float2 hl = ((const float2*)hlin)[mh];
    const float2 tl = ((const float2*)tlin)[mt];
    const float2 zz = *(const float2*)(Stab + (size_t)mh * 1024 + 2 * t);
    const float z0 = zz.x + hl.x + tl.x + lin_b[0];
    const float z1 = zz.y + hl.y + tl.y + lin_b[1];
    out[1 + 2 * (size_t)i] = z0;
    out[2 + 2 * (size_t)i] = z1;

    const float mx = fmaxf(z0, z1);
    const float mn = fminf(z0, z1);
    const float lse = mx + log1pf(expf(mn - mx));
    float ce = lse - (lab ? z1 : z0);

    // block reduce (4 waves) then one atomic into out[0]
    #pragma unroll
    for (int o = 32; o >= 1; o >>= 1) ce += __shfl_xor(ce, o, 64);
    __shared__ float wsum[4];
    if ((tid & 63) == 0) wsum[tid >> 6] = ce;
    __syncthreads();
    if (tid == 0) {
        const float bs = wsum[0] + wsum[1] + wsum[2] + wsum[3];
        atomicAdd(out, bs * (1.0f / (float)RR));
    }
}

// ---------------------------------------------------------------------------
extern "C" void kernel_launch(void* const* d_in, const int* in_sizes, int n_in,
                              void* d_out, int out_size, void* d_ws, size_t ws_size,
                              hipStream_t stream) {
    const float* hidden    = (const float*)d_in[0];
    const int*   ent_start = (const int*)d_in[1];
    const int*   ent_label = (const int*)d_in[2];
    const int*   rel_head  = (const int*)d_in[3];
    const int*   rel_tail  = (const int*)d_in[4];
    const int*   rel_label = (const int*)d_in[5];
    const float* emb       = (const float*)d_in[6];
    const float* head_W1   = (const float*)d_in[7];
    const float* head_b1   = (const float*)d_in[8];
    const float* head_W2   = (const float*)d_in[9];
    const float* head_b2   = (const float*)d_in[10];
    const float* tail_W1   = (const float*)d_in[11];
    const float* tail_b1   = (const float*)d_in[12];
    const float* tail_W2   = (const float*)d_in[13];
    const float* tail_b2   = (const float*)d_in[14];
    const float* bil_W     = (const float*)d_in[15];
    const float* lin_W     = (const float*)d_in[16];
    const float* lin_b     = (const float*)d_in[17];
    float* out = (float*)d_out;

    // Workspace carve-up (256B-aligned chunks)
    char* w = (char*)d_ws;
    auto carve = [&](size_t bytes) {
        char* p = w; w += (bytes + 255) & ~(size_t)255; return p;
    };
    unsigned short* Hbf  = (unsigned short*)carve((size_t)MM * 768 * 2);
    unsigned short* Y1bf = (unsigned short*)carve((size_t)MM * 1536 * 2);
    unsigned short* HTbf = (unsigned short*)carve((size_t)MM * 768 * 2);
    unsigned short* hWbf = (unsigned short*)carve((size_t)MM * 768 * 2);
    float*          Stab = (float*)carve((size_t)MM * 1024 * 4);
    unsigned short* W1ht = (unsigned short*)carve((size_t)768 * 768 * 2);
    unsigned short* W1tt = (unsigned short*)carve((size_t)768 * 768 * 2);
    unsigned short* W2ht = (unsigned short*)carve((size_t)384 * 768 * 2);
    unsigned short* W2tt = (unsigned short*)carve((size_t)384 * 768 * 2);
    unsigned short* bW0t = (unsigned short*)carve((size_t)384 * 384 * 2);
    unsigned short* bW1t = (unsigned short*)carve((size_t)384 * 384 * 2);
    float*          embc = (float*)carve((size_t)3 * 1536 * 4);
    float*          hlin = (float*)carve(2048 * 4);
    float*          tlin = (float*)carve(2048 * 4);

    // 1) W1 transpose + hidden gather + embc fold + zeroing
    prep<<<2201, 256, 0, stream>>>(
        head_W1, tail_W1, W1ht, W1tt,
        hidden, ent_start, emb, head_b1, tail_b1, Hbf, embc,
        hlin, tlin, out);

    // 2) layer1 (384 tiles) + overlapped W2/bil transposes (864 blocks)
    gemm1_plus<<<1248, 256, 0, stream>>>(
        Hbf, W1ht, W1tt, embc, ent_label, Y1bf,
        head_W2, tail_W2, bil_W, W2ht, W2tt, bW0t, bW1t);

    // 3) layer2: HTbf = relu(Y1 @ [W2h|W2t] + b2), N=768 (Nh=384), K=768,
    //    tail half reads Y1 cols 768..; epilogue fuses lin_proj via atomics
    gemm_mfma<true, true, false, false, true, false, true>
        <<<dim3(12, 16), 256, 0, stream>>>(
        Y1bf, 1536, 768, W2ht, W2tt, 768, 0, 384, head_b2, tail_b2,
        nullptr, nullptr, lin_W, hlin, tlin, 768, nullptr, HTbf, 768);

    // 4) bilinear left product: hWbf = heads @ bil_W[o], N=768 (Nh=384), K=384
    gemm_mfma<false, false, false, false, true, false, false>
        <<<dim3(12, 16), 256, 0, stream>>>(
        HTbf, 768, 0, bW0t, bW1t, 384, 0, 384, nullptr, nullptr,
        nullptr, nullptr, nullptr, nullptr, nullptr, 384, nullptr, hWbf, 768);

    // 5) score table (o-interleaved): Stab[mh][2t+o] = hWbf[mh, o*384:..] . tails
    gemm_mfma<false, false, false, true, false, true, false>
        <<<dim3(16, 16), 256, 0, stream>>>(
        hWbf, 768, 384, HTbf + 384, HTbf + 384, 768, 512, 512,
        nullptr, nullptr, nullptr, nullptr, nullptr, nullptr, nullptr,
        384, Stab, nullptr, 1024);

    // 6) per-relation gather + CE + fused loss reduction
    rel_gather<<<256, 256, 0, stream>>>(Stab, hlin, tlin, lin_b,
                                        rel_head, rel_tail, rel_label, out);
}

// Round 6
// 143.051 us; speedup vs baseline: 2.6925x; 1.0306x over previous
//
#include <hip/hip_runtime.h>
#include <math.h>

// Problem constants
#define BB 2
#define LL 512
#define HH 768
#define EE 512
#define RR 32768
#define H2 384
#define MM 1024   // B*E entity rows

typedef __attribute__((ext_vector_type(8))) short     bf16x8;  // MFMA A/B frag
typedef __attribute__((ext_vector_type(4))) float     f32x4;   // MFMA C/D frag
typedef __attribute__((ext_vector_type(8))) unsigned short u16x8;

#define BUFE (64 * 72)    // one LDS buffer: 64 rows x (64+8) bf16

__device__ __forceinline__ unsigned short f2bf(float f) {
    unsigned int u = __float_as_uint(f);
    u = (u + 0x7FFFu + ((u >> 16) & 1u)) >> 16;   // round-to-nearest-even
    return (unsigned short)u;
}

// ---------------------------------------------------------------------------
// 32x32 weight transpose tile: [K][N] fp32 -> [N][K] bf16. T = 32*40 ushorts.
// ---------------------------------------------------------------------------
__device__ __forceinline__ void wtrans(const float* __restrict__ src,
                                       unsigned short* __restrict__ dst,
                                       int K, int N, int tile, unsigned short* T)
{
    const int t = threadIdx.x;
    const int tn = N >> 5;
    const int n0 = (tile % tn) * 32;
    const int k0 = (tile / tn) * 32;
    const int r  = t >> 3;           // 0..31 (k within tile)
    const int c4 = (t & 7) * 4;      // 0..28 (n within tile)
    const float4 g = *(const float4*)(src + (size_t)(k0 + r) * N + n0 + c4);
    T[(c4 + 0) * 40 + r] = f2bf(g.x);
    T[(c4 + 1) * 40 + r] = f2bf(g.y);
    T[(c4 + 2) * 40 + r] = f2bf(g.z);
    T[(c4 + 3) * 40 + r] = f2bf(g.w);
    __syncthreads();
    const int n  = t >> 3;           // 0..31
    const int k4 = (t & 7) * 4;      // 0..28
    *(ushort4*)(dst + (size_t)(n0 + n) * K + k0 + k4) = *(ushort4*)&T[n * 40 + k4];
}

// ---------------------------------------------------------------------------
// prep:
//   [0,576)     W1 head top-half transpose -> W1ht
//   [576,1152)  W1 tail top-half transpose -> W1tt
//   [1152,2176) gather hidden[b, ent_start] -> Hbf bf16 [1024][768]
//   [2176,2200) embc[l][n] = b1[n] + sum_k emb[l][k]*W1[768+k][n]
//   2200        zero hlin/tlin accumulators + out[0]
// ---------------------------------------------------------------------------
__global__ __launch_bounds__(256) void prep(
    const float* __restrict__ hW1, const float* __restrict__ tW1,
    unsigned short* __restrict__ W1ht, unsigned short* __restrict__ W1tt,
    const float* __restrict__ hidden, const int* __restrict__ ent_start,
    const float* __restrict__ emb,
    const float* __restrict__ hb1, const float* __restrict__ tb1,
    unsigned short* __restrict__ Hbf, float* __restrict__ embc,
    float* __restrict__ hlin, float* __restrict__ tlin, float* __restrict__ out)
{
    __shared__ unsigned short T[32 * 40];
    __shared__ float red[4][192];
    const int bid = blockIdx.x;
    const int t = threadIdx.x;

    if (bid == 2200) {
        const float4 z = {0.f, 0.f, 0.f, 0.f};
        ((float4*)hlin)[t] = z; ((float4*)hlin)[256 + t] = z;
        ((float4*)tlin)[t] = z; ((float4*)tlin)[256 + t] = z;
        if (t == 0) out[0] = 0.f;
        return;
    }

    if (bid >= 2176) {
        // ---- embc: per-(label, col) folded bias table
        const int eb = bid - 2176;           // 0..23
        const int tc = t & 63;
        const int kg = t >> 6;               // 0..3 k-group
        const int n = eb * 64 + tc;          // global col 0..1535
        const float* W = (n < 768) ? hW1 : tW1;
        const int cc = (n < 768) ? n : n - 768;
        float a0 = 0.f, a1 = 0.f, a2 = 0.f;
        const int kbeg = kg * 192;
        #pragma unroll 8
        for (int k = kbeg; k < kbeg + 192; ++k) {
            const float w = W[(size_t)(768 + k) * 768 + cc];
            a0 += emb[k] * w;
            a1 += emb[768 + k] * w;
            a2 += emb[1536 + k] * w;
        }
        red[kg][0 * 64 + tc] = a0;
        red[kg][1 * 64 + tc] = a1;
        red[kg][2 * 64 + tc] = a2;
        __syncthreads();
        if (kg == 0) {
            const float b = (n < 768) ? hb1[n] : tb1[n - 768];
            #pragma unroll
            for (int l = 0; l < 3; ++l) {
                embc[l * 1536 + n] = b + red[0][l * 64 + tc] + red[1][l * 64 + tc]
                                       + red[2][l * 64 + tc] + red[3][l * 64 + tc];
            }
        }
        return;
    }

    if (bid >= 1152) {
        // ---- gather hidden[b, ent_start[m]] as bf16 (768 cols)
        const int m = bid - 1152;            // 0..1023
        if (t >= 96) return;
        const int b = m >> 9;
        const int idx = ent_start[m];
        const float4* s = (const float4*)(hidden + (size_t)(b * LL + idx) * HH);
        const float4 v0 = s[2 * t];
        const float4 v1 = s[2 * t + 1];
        u16x8 o;
        o[0] = f2bf(v0.x); o[1] = f2bf(v0.y); o[2] = f2bf(v0.z); o[3] = f2bf(v0.w);
        o[4] = f2bf(v1.x); o[5] = f2bf(v1.y); o[6] = f2bf(v1.z); o[7] = f2bf(v1.w);
        *(u16x8*)(Hbf + (size_t)m * 768 + 8 * t) = o;
        return;
    }

    // ---- W1 transposes (top halves only; bottom folded into embc)
    if (bid < 576) wtrans(hW1, W1ht, 768, 768, bid, T);
    else           wtrans(tW1, W1tt, 768, 768, bid - 576, T);
}

// ---------------------------------------------------------------------------
// bf16 MFMA GEMM body. 64x64 tile, 256 threads (4 waves, 2x2), 16x16x32 MFMA.
// K_STEP=64, double-buffered LDS, ONE raw s_barrier per K-step, and a
// TWO-DEEP register prefetch pipeline: loads for step it+2 are issued at
// step it, so the ds_write of step it+1's data waits on a COUNTED vmcnt(4)
// (compiler-inserted) with a full iteration of cover — loads stay in flight
// across the barrier instead of draining every step.
// NT = K/64 must be EVEN (all call sites: 6 or 12).
// ---------------------------------------------------------------------------
template<bool RELU, bool BIAS, bool EB, bool WF32, bool WBF16, bool O2, bool LIN>
__device__ __forceinline__ void gemm_body(
    int tile, int nx,
    const unsigned short* __restrict__ A, int lda, int aoff1,
    const unsigned short* __restrict__ Bt0, const unsigned short* __restrict__ Bt1,
    int ldb, int bt_mrow, int Nh,
    const float* __restrict__ bias0, const float* __restrict__ bias1,
    const float* __restrict__ embc, const int* __restrict__ labels,
    const float* __restrict__ linW, float* __restrict__ hlin, float* __restrict__ tlin,
    int K, float* __restrict__ Cf, unsigned short* __restrict__ Cb, int ldc,
    unsigned short* As, unsigned short* Bs)
{
    const int tid = threadIdx.x;
    const int n0 = (tile % nx) * 64;
    const int m0 = (tile / nx) * 64;
    const int hf = (n0 >= Nh) ? 1 : 0;
    const unsigned short* Bt = hf ? Bt1 : Bt0;
    const int nc0 = n0 - (hf ? Nh : 0);
    const int aoff = hf ? aoff1 : 0;

    // staging: thread t covers row sr, 16 bf16 at k-offset sk (2 x u16x8)
    const int sr = tid >> 2;            // 0..63
    const int sk = (tid & 3) * 16;      // 0,16,32,48

    const unsigned short* Ap = A + (size_t)(m0 + sr) * lda + aoff + sk;
    const unsigned short* Bp = Bt + (size_t)((m0 >> 9) * bt_mrow + nc0 + sr) * ldb + sk;

    const int lane = tid & 63;
    const int wave = tid >> 6;
    const int wm = (wave & 1) * 32;
    const int wn = (wave >> 1) * 32;
    const int l15 = lane & 15;
    const int quad = lane >> 4;
    const int swo = sr * 72 + sk;
    const int aro = quad * 8;

    f32x4 acc00 = {}, acc01 = {}, acc10 = {}, acc11 = {};

    // two register stage-sets (2-deep prefetch)
    u16x8 pa0, pa1, pb0, pb1;           // even K-steps
    u16x8 qa0, qa1, qb0, qb1;           // odd K-steps

#define GLOADP(ko) { pa0 = *(const u16x8*)(Ap + (ko)); pa1 = *(const u16x8*)(Ap + (ko) + 8); \
                     pb0 = *(const u16x8*)(Bp + (ko)); pb1 = *(const u16x8*)(Bp + (ko) + 8); }
#define GLOADQ(ko) { qa0 = *(const u16x8*)(Ap + (ko)); qa1 = *(const u16x8*)(Ap + (ko) + 8); \
                     qb0 = *(const u16x8*)(Bp + (ko)); qb1 = *(const u16x8*)(Bp + (ko) + 8); }
#define SWRITEP(bi) { unsigned short* Aw = As + (bi) * BUFE; unsigned short* Bw = Bs + (bi) * BUFE; \
                      *(u16x8*)&Aw[swo] = pa0; *(u16x8*)&Aw[swo + 8] = pa1; \
                      *(u16x8*)&Bw[swo] = pb0; *(u16x8*)&Bw[swo + 8] = pb1; }
#define SWRITEQ(bi) { unsigned short* Aw = As + (bi) * BUFE; unsigned short* Bw = Bs + (bi) * BUFE; \
                      *(u16x8*)&Aw[swo] = qa0; *(u16x8*)&Aw[swo + 8] = qa1; \
                      *(u16x8*)&Bw[swo] = qb0; *(u16x8*)&Bw[swo + 8] = qb1; }
#define BAR() { asm volatile("s_waitcnt lgkmcnt(0)" ::: "memory"); \
                __builtin_amdgcn_s_barrier(); \
                __builtin_amdgcn_sched_barrier(0); }
#define MFMA8(bi) { const unsigned short* Ac = As + (bi) * BUFE; \
                    const unsigned short* Bc = Bs + (bi) * BUFE; \
        const bf16x8 fa0 = *(const bf16x8*)&Ac[(wm + l15) * 72 + aro]; \
        const bf16x8 fa1 = *(const bf16x8*)&Ac[(wm + 16 + l15) * 72 + aro]; \
        const bf16x8 fb0 = *(const bf16x8*)&Bc[(wn + l15) * 72 + aro]; \
        const bf16x8 fb1 = *(const bf16x8*)&Bc[(wn + 16 + l15) * 72 + aro]; \
        const bf16x8 ga0 = *(const bf16x8*)&Ac[(wm + l15) * 72 + aro + 32]; \
        const bf16x8 ga1 = *(const bf16x8*)&Ac[(wm + 16 + l15) * 72 + aro + 32]; \
        const bf16x8 gb0 = *(const bf16x8*)&Bc[(wn + l15) * 72 + aro + 32]; \
        const bf16x8 gb1 = *(const bf16x8*)&Bc[(wn + 16 + l15) * 72 + aro + 32]; \
        acc00 = __builtin_amdgcn_mfma_f32_16x16x32_bf16(fa0, fb0, acc00, 0, 0, 0); \
        acc01 = __builtin_amdgcn_mfma_f32_16x16x32_bf16(fa0, fb1, acc01, 0, 0, 0); \
        acc10 = __builtin_amdgcn_mfma_f32_16x16x32_bf16(fa1, fb0, acc10, 0, 0, 0); \
        acc11 = __builtin_amdgcn_mfma_f32_16x16x32_bf16(fa1, fb1, acc11, 0, 0, 0); \
        acc00 = __builtin_amdgcn_mfma_f32_16x16x32_bf16(ga0, gb0, acc00, 0, 0, 0); \
        acc01 = __builtin_amdgcn_mfma_f32_16x16x32_bf16(ga0, gb1, acc01, 0, 0, 0); \
        acc10 = __builtin_amdgcn_mfma_f32_16x16x32_bf16(ga1, gb0, acc10, 0, 0, 0); \
        acc11 = __builtin_amdgcn_mfma_f32_16x16x32_bf16(ga1, gb1, acc11, 0, 0, 0); }

    const int NT = K >> 6;              // even (6 or 12)

    // prologue: issue K0 and K1 loads; stage K0 into buf0 (vmcnt(4) wait —
    // K1's loads remain in flight across the first barrier)
    GLOADP(0);
    GLOADQ(64);
    SWRITEP(0);

    for (int it = 0; it < NT; it += 2) {
        // even step: compute buf0, issue K(it+2), stage K(it+1) into buf1
        BAR();
        if (it + 2 < NT) GLOADP((it + 2) << 6);
        MFMA8(0);
        SWRITEQ(1);                      // vmcnt(4): waits K(it+1) only
        // odd step: compute buf1, issue K(it+3), stage K(it+2) into buf0
        BAR();
        if (it + 3 < NT) GLOADQ((it + 3) << 6);
        MFMA8(1);
        if (it + 2 < NT) SWRITEP(0);     // vmcnt(4): waits K(it+2) only
    }

#undef GLOADP
#undef GLOADQ
#undef SWRITEP
#undef SWRITEQ
#undef BAR
#undef MFMA8

    // epilogue: C/D layout col=lane&15, row=quad*4+reg
    float bias_v0 = 0.f, bias_v1 = 0.f;
    if (BIAS) {
        const float* bb = hf ? bias1 : bias0;
        bias_v0 = bb[nc0 + wn + l15];
        bias_v1 = bb[nc0 + wn + 16 + l15];
    }
    const int col0 = n0 + wn + l15;
    const int col1 = col0 + 16;
    int colw0 = col0, colw1 = col1;
    if (O2) {
        colw0 = 2 * (nc0 + wn + l15) + hf;
        colw1 = 2 * (nc0 + wn + 16 + l15) + hf;
    }
    float2 lw0 = {0.f, 0.f}, lw1 = {0.f, 0.f};
    float* lout = nullptr;
    if (LIN) {
        lw0 = ((const float2*)linW)[col0];
        lw1 = ((const float2*)linW)[col1];
        lout = hf ? tlin : hlin;
    }
    const f32x4 accs[2][2] = {{acc00, acc01}, {acc10, acc11}};
    #pragma unroll
    for (int mi = 0; mi < 2; ++mi) {
        #pragma unroll
        for (int r = 0; r < 4; ++r) {
            const int row = m0 + wm + mi * 16 + quad * 4 + r;
            float v0 = accs[mi][0][r];
            float v1 = accs[mi][1][r];
            if (BIAS) { v0 += bias_v0; v1 += bias_v1; }
            if (EB) {
                const int lab = labels[row];
                v0 += embc[lab * 1536 + col0];
                v1 += embc[lab * 1536 + col1];
            }
            if (RELU) { v0 = fmaxf(v0, 0.f); v1 = fmaxf(v1, 0.f); }
            if (WF32) {
                Cf[(size_t)row * ldc + colw0] = v0;
                Cf[(size_t)row * ldc + colw1] = v1;
            }
            if (WBF16) {
                Cb[(size_t)row * ldc + colw0] = f2bf(v0);
                Cb[(size_t)row * ldc + colw1] = f2bf(v1);
            }
            if (LIN) {
                float s0 = v0 * lw0.x + v1 * lw1.x;
                float s1 = v0 * lw0.y + v1 * lw1.y;
                #pragma unroll
                for (int o = 8; o >= 1; o >>= 1) {
                    s0 += __shfl_xor(s0, o, 64);
                    s1 += __shfl_xor(s1, o, 64);
                }
                if (l15 == 0) {
                    atomicAdd(&lout[2 * row],     s0);
                    atomicAdd(&lout[2 * row + 1], s1);
                }
            }
        }
    }
}

// Generic GEMM kernel (stages 3-5), 2-D grid.
template<bool RELU, bool BIAS, bool EB, bool WF32, bool WBF16, bool O2, bool LIN>
__global__ __launch_bounds__(256) void gemm_mfma(
    const unsigned short* __restrict__ A, int lda, int aoff1,
    const unsigned short* __restrict__ Bt0, const unsigned short* __restrict__ Bt1,
    int ldb, int bt_mrow, int Nh,
    const float* __restrict__ bias0, const float* __restrict__ bias1,
    const float* __restrict__ embc, const int* __restrict__ labels,
    const float* __restrict__ linW, float* __restrict__ hlin, float* __restrict__ tlin,
    int K, float* __restrict__ Cf, unsigned short* __restrict__ Cb, int ldc)
{
    __shared__ __align__(16) unsigned short As[2 * BUFE];
    __shared__ __align__(16) unsigned short Bs[2 * BUFE];
    gemm_body<RELU, BIAS, EB, WF32, WBF16, O2, LIN>(
        blockIdx.y * gridDim.x + blockIdx.x, gridDim.x,
        A, lda, aoff1, Bt0, Bt1, ldb, bt_mrow, Nh,
        bias0, bias1, embc, labels, linW, hlin, tlin,
        K, Cf, Cb, ldc, As, Bs);
}

// ---------------------------------------------------------------------------
// gemm1 + overlapped W2/bil transposes: blocks [0,384) = layer1 tiles,
// blocks [384,1248) = weight transposes consumed only by later launches.
// ---------------------------------------------------------------------------
__global__ __launch_bounds__(256) void gemm1_plus(
    const unsigned short* __restrict__ Hbf,
    const unsigned short* __restrict__ W1ht, const unsigned short* __restrict__ W1tt,
    const float* __restrict__ embc, const int* __restrict__ ent_label,
    unsigned short* __restrict__ Y1bf,
    const float* __restrict__ hW2, const float* __restrict__ tW2,
    const float* __restrict__ bilW,
    unsigned short* __restrict__ W2ht, unsigned short* __restrict__ W2tt,
    unsigned short* __restrict__ bW0t, unsigned short* __restrict__ bW1t)
{
    __shared__ __align__(16) unsigned short As[2 * BUFE];
    __shared__ __align__(16) unsigned short Bs[2 * BUFE];
    const int bid = blockIdx.x;
    if (bid >= 384) {
        const int task = bid - 384;
        if (task < 288)      wtrans(hW2, W2ht, 768, 384, task, As);
        else if (task < 576) wtrans(tW2, W2tt, 768, 384, task - 288, As);
        else if (task < 720) wtrans(bilW, bW0t, 384, 384, task - 576, As);
        else                 wtrans(bilW + 384 * 384, bW1t, 384, 384, task - 720, As);
        return;
    }
    gemm_body<true, false, true, false, true, false, false>(
        bid, 24, Hbf, 768, 0, W1ht, W1tt, 768, 0, 768,
        nullptr, nullptr, embc, ent_label, nullptr, nullptr, nullptr,
        768, nullptr, Y1bf, 1536, As, Bs);
}

// ---------------------------------------------------------------------------
// Per-relation gather from the score table + CE reduction (fused loss).
// One thread per relation. Stab interleaved: Stab[mh][2*t + o].
// ---------------------------------------------------------------------------
__global__ __launch_bounds__(256) void rel_gather(
    const float* __restrict__ Stab,
    const float* __restrict__ hlin, const float* __restrict__ tlin,
    const float* __restrict__ lin_b,
    const int* __restrict__ rel_head, const int* __restrict__ rel_tail,
    const int* __restrict__ rel_label,
    float* __restrict__ out)
{
    const int tid = threadIdx.x;
    const int i = blockIdx.x * 256 + tid;       // relation 0..65535
    const int b = i >> 15;
    const int h = rel_head[i];
    const int t = rel_tail[i];
    const int lab = rel_label[i];
    const int mh = (b << 9) + h;
    const int mt = (b << 9) + t;

    const float2 hl = ((const float2*)hlin)[mh];
    const float2 tl = ((const float2*)tlin)[mt];
    const float2 zz = *(const float2*)(Stab + (size_t)mh * 1024 + 2 * t);
    const float z0 = zz.x + hl.x + tl.x + lin_b[0];
    const float z1 = zz.y + hl.y + tl.y + lin_b[1];
    out[1 + 2 * (size_t)i] = z0;
    out[2 + 2 * (size_t)i] = z1;

    const float mx = fmaxf(z0, z1);
    const float mn = fminf(z0, z1);
    const float lse = mx + log1pf(expf(mn - mx));
    float ce = lse - (lab ? z1 : z0);

    // block reduce (4 waves) then one atomic into out[0]
    #pragma unroll
    for (int o = 32; o >= 1; o >>= 1) ce += __shfl_xor(ce, o, 64);
    __shared__ float wsum[4];
    if ((tid & 63) == 0) wsum[tid >> 6] = ce;
    __syncthreads();
    if (tid == 0) {
        const float bs = wsum[0] + wsum[1] + wsum[2] + wsum[3];
        atomicAdd(out, bs * (1.0f / (float)RR));
    }
}

// ---------------------------------------------------------------------------
extern "C" void kernel_launch(void* const* d_in, const int* in_sizes, int n_in,
                              void* d_out, int out_size, void* d_ws, size_t ws_size,
                              hipStream_t stream) {
    const float* hidden    = (const float*)d_in[0];
    const int*   ent_start = (const int*)d_in[1];
    const int*   ent_label = (const int*)d_in[2];
    const int*   rel_head  = (const int*)d_in[3];
    const int*   rel_tail  = (const int*)d_in[4];
    const int*   rel_label = (const int*)d_in[5];
    const float* emb       = (const float*)d_in[6];
    const float* head_W1   = (const float*)d_in[7];
    const float* head_b1   = (const float*)d_in[8];
    const float* head_W2   = (const float*)d_in[9];
    const float* head_b2   = (const float*)d_in[10];
    const float* tail_W1   = (const float*)d_in[11];
    const float* tail_b1   = (const float*)d_in[12];
    const float* tail_W2   = (const float*)d_in[13];
    const float* tail_b2   = (const float*)d_in[14];
    const float* bil_W     = (const float*)d_in[15];
    const float* lin_W     = (const float*)d_in[16];
    const float* lin_b     = (const float*)d_in[17];
    float* out = (float*)d_out;

    // Workspace carve-up (256B-aligned chunks)
    char* w = (char*)d_ws;
    auto carve = [&](size_t bytes) {
        char* p = w; w += (bytes + 255) & ~(size_t)255; return p;
    };
    unsigned short* Hbf  = (unsigned short*)carve((size_t)MM * 768 * 2);
    unsigned short* Y1bf = (unsigned short*)carve((size_t)MM * 1536 * 2);
    unsigned short* HTbf = (unsigned short*)carve((size_t)MM * 768 * 2);
    unsigned short* hWbf = (unsigned short*)carve((size_t)MM * 768 * 2);
    float*          Stab = (float*)carve((size_t)MM * 1024 * 4);
    unsigned short* W1ht = (unsigned short*)carve((size_t)768 * 768 * 2);
    unsigned short* W1tt = (unsigned short*)carve((size_t)768 * 768 * 2);
    unsigned short* W2ht = (unsigned short*)carve((size_t)384 * 768 * 2);
    unsigned short* W2tt = (unsigned short*)carve((size_t)384 * 768 * 2);
    unsigned short* bW0t = (unsigned short*)carve((size_t)384 * 384 * 2);
    unsigned short* bW1t = (unsigned short*)carve((size_t)384 * 384 * 2);
    float*          embc = (float*)carve((size_t)3 * 1536 * 4);
    float*          hlin = (float*)carve(2048 * 4);
    float*          tlin = (float*)carve(2048 * 4);

    // 1) W1 transpose + hidden gather + embc fold + zeroing
    prep<<<2201, 256, 0, stream>>>(
        head_W1, tail_W1, W1ht, W1tt,
        hidden, ent_start, emb, head_b1, tail_b1, Hbf, embc,
        hlin, tlin, out);

    // 2) layer1 (384 tiles) + overlapped W2/bil transposes (864 blocks)
    gemm1_plus<<<1248, 256, 0, stream>>>(
        Hbf, W1ht, W1tt, embc, ent_label, Y1bf,
        head_W2, tail_W2, bil_W, W2ht, W2tt, bW0t, bW1t);

    // 3) layer2: HTbf = relu(Y1 @ [W2h|W2t] + b2), N=768 (Nh=384), K=768,
    //    tail half reads Y1 cols 768..; epilogue fuses lin_proj via atomics
    gemm_mfma<true, true, false, false, true, false, true>
        <<<dim3(12, 16), 256, 0, stream>>>(
        Y1bf, 1536, 768, W2ht, W2tt, 768, 0, 384, head_b2, tail_b2,
        nullptr, nullptr, lin_W, hlin, tlin, 768, nullptr, HTbf, 768);

    // 4) bilinear left product: hWbf = heads @ bil_W[o], N=768 (Nh=384), K=384
    gemm_mfma<false, false, false, false, true, false, false>
        <<<dim3(12, 16), 256, 0, stream>>>(
        HTbf, 768, 0, bW0t, bW1t, 384, 0, 384, nullptr, nullptr,
        nullptr, nullptr, nullptr, nullptr, nullptr, 384, nullptr, hWbf, 768);

    // 5) score table (o-interleaved): Stab[mh][2t+o] = hWbf[mh, o*384:..] . tails
    gemm_mfma<false, false, false, true, false, true, false>
        <<<dim3(16, 16), 256, 0, stream>>>(
        hWbf, 768, 384, HTbf + 384, HTbf + 384, 768, 512, 512,
        nullptr, nullptr, nullptr, nullptr, nullptr, nullptr, nullptr,
        384, Stab, nullptr, 1024);

    // 6) per-relation gather + CE + fused loss reduction
    rel_gather<<<256, 256, 0, stream>>>(Stab, hlin, tlin, lin_b,
                                        rel_head, rel_tail, rel_label, out);
}